// Round 9
// baseline (286.701 us; speedup 1.0000x reference)
//
#include <hip/hip_runtime.h>
#include <hip/hip_bf16.h>

#define RREL 4
#define DIM 256
#define KDIM 1280      // 4*DIM (means) + DIM (self)
#define KMEAN 1024     // means-only K extent of Y
#define BCAP 32        // bucket capacity per (r,dst) segment

__device__ __forceinline__ float bf2f(unsigned short u) {
    union { unsigned int i; float f; } z; z.i = ((unsigned int)u) << 16; return z.f;
}
__device__ __forceinline__ unsigned short f2bf(float f) {
    __hip_bfloat16 h = __float2bfloat16(f);
    return *(unsigned short*)&h;
}

typedef __attribute__((ext_vector_type(8))) short bf16x8;
typedef __attribute__((ext_vector_type(8))) unsigned short u16x8;
typedef __attribute__((ext_vector_type(4))) float f32x4;
typedef __attribute__((ext_vector_type(4))) float fx4;
typedef __attribute__((ext_vector_type(4))) int ix4;

// ---------------- fused prep: bucket-scatter + x->bf16 cast + weight transpose ----------
// No CSR scan: per-(r,dst) fixed-capacity bucket; counts doubles as cursor & final count.

__global__ __launch_bounds__(256)
void prep(const int* __restrict__ etype, const int* __restrict__ src,
          const int* __restrict__ dst,
          int* __restrict__ counts, int* __restrict__ bucket, int N, int E,
          const float* __restrict__ x, __hip_bfloat16* __restrict__ xb, int n4,
          const float* __restrict__ W0, const float* __restrict__ root0,
          const float* __restrict__ W1, const float* __restrict__ root1,
          __hip_bfloat16* __restrict__ WT,
          int eb, int cb) {
    int b = blockIdx.x;
    if (b < eb) {                       // count + scatter into buckets
        int e = b * 256 + threadIdx.x;
        if (e < E) {
            int seg = etype[e] * N + dst[e];
            int p = atomicAdd(&counts[seg], 1);
            if (p < BCAP) bucket[(size_t)seg * BCAP + p] = src[e];
        }
    } else if (b < eb + cb) {           // cast x -> bf16
        int i = (b - eb) * 256 + threadIdx.x;
        if (i < n4) {
            fx4 v = __builtin_nontemporal_load((const fx4*)x + i);
            ushort4 u = make_ushort4(f2bf(v.x), f2bf(v.y), f2bf(v.z), f2bf(v.w));
            ((ushort4*)xb)[i] = u;
        }
    } else {                            // WT[layer][n=0..255][k=0..1279] n-major
        __shared__ float tile[32][33];
        int q = b - eb - cb;
        int layer = q / 320; q -= layer * 320;
        int nblk = q / 40;              // 0..7   (n0 over 256)
        int kblk = q - nblk * 40;       // 0..39  (k0 over 1280)
        const float* Wm = layer ? W1 : W0;
        const float* Rm = layer ? root1 : root0;
        int k0 = kblk * 32, n0 = nblk * 32;
        int tx = threadIdx.x & 31, ty = threadIdx.x >> 5;   // 32x8
        const float* srcp;
        int kbase;
        if (k0 < RREL * DIM) { srcp = Wm; kbase = k0; } else { srcp = Rm; kbase = k0 - RREL * DIM; }
#pragma unroll
        for (int j = 0; j < 4; j++) {
            int k = kbase + ty + j * 8;
            tile[ty + j * 8][tx] = __builtin_nontemporal_load(srcp + (size_t)k * DIM + n0 + tx);
        }
        __syncthreads();
#pragma unroll
        for (int j = 0; j < 4; j++) {
            int n = n0 + ty + j * 8;
            WT[((size_t)layer * DIM + n) * KDIM + k0 + tx] = __float2bfloat16(tile[tx][ty + j * 8]);
        }
    }
}

// ---------------- aggregation: Y[i,r*256:+256] = mean_r(feat)  (bf16) ----------------
// Block = node pair, wave = relation, half-wave = node (32 lanes x 8 dims = 256).
// Masked quad: one int4 bucket load + 4 independent 16B row loads in flight.
// NT hints: bucket loads + Y stores bypass L2 so the feat table stays resident
// (R2/R4 evidence: FETCH ~= requested bytes -> L2 hit ~0 due to write pollution).

__global__ __launch_bounds__(256)
void aggregate(const __hip_bfloat16* __restrict__ feat, const int* __restrict__ counts,
               const int* __restrict__ bucket, __hip_bfloat16* __restrict__ Y, int N) {
    int r = threadIdx.x >> 6, lane = threadIdx.x & 63;
    int h = lane >> 5, li = lane & 31;
    int i = blockIdx.x * 2 + h;
    if (i >= N) return;
    int seg = r * N + i;
    int cnt = min(counts[seg], BCAP);
    const unsigned short* fu = (const unsigned short*)feat;
    const int* bk = bucket + (size_t)seg * BCAP;
    float a[8] = {};
    for (int k = 0; k < cnt; k += 4) {
        ix4 q = __builtin_nontemporal_load((const ix4*)(bk + k));
        float m1 = (k + 1 < cnt) ? 1.f : 0.f;
        float m2 = (k + 2 < cnt) ? 1.f : 0.f;
        float m3 = (k + 3 < cnt) ? 1.f : 0.f;
        int i0 = q.x;
        int i1 = m1 ? q.y : q.x;                   // clamp to a valid row address
        int i2 = m2 ? q.z : q.x;
        int i3 = m3 ? q.w : q.x;
        u16x8 v0 = *(const u16x8*)(fu + (size_t)i0 * DIM + li * 8);
        u16x8 v1 = *(const u16x8*)(fu + (size_t)i1 * DIM + li * 8);
        u16x8 v2 = *(const u16x8*)(fu + (size_t)i2 * DIM + li * 8);
        u16x8 v3 = *(const u16x8*)(fu + (size_t)i3 * DIM + li * 8);
#pragma unroll
        for (int j = 0; j < 8; j++)
            a[j] += bf2f(v0[j]) + m1 * bf2f(v1[j]) + m2 * bf2f(v2[j]) + m3 * bf2f(v3[j]);
    }
    float inv = (cnt > 0) ? 1.f / (float)cnt : 0.f;
    u16x8 u;
#pragma unroll
    for (int j = 0; j < 8; j++) u[j] = f2bf(a[j] * inv);
    __builtin_nontemporal_store(u, (u16x8*)((unsigned short*)Y + (size_t)i * KMEAN + r * DIM + li * 8));
}

// ---------------- MFMA GEMM, double-buffered, full-width N ----------------
// C[N,256] = [Y | self] @ WT^T + bias.  BM=64, BN=256 (Y fetched once), BK=64.
// MODE 0: write bf16 + ReLU (nt).  MODE 1: no C write; fused column-sum atomicAdd.

#define BMg 64
#define BKg 64

template <int MODE>
__global__ __launch_bounds__(256)
void gemm_mfma(const __hip_bfloat16* __restrict__ A,     // [Mpad, 1024] means
               const __hip_bfloat16* __restrict__ Aself, // [Mpad, 256] feature table
               const __hip_bfloat16* __restrict__ Bt,    // [256, 1280] n-major
               const float* __restrict__ bias,           // [256]
               unsigned short* __restrict__ Cbf,         // [N, 256] (MODE 0)
               float* __restrict__ gsum,                 // [256]    (MODE 1)
               int Nrows) {
    __shared__ short As[2][BMg * BKg];       // 2 x 8 KB
    __shared__ short Bs[2][DIM * BKg];       // 2 x 32 KB
    int t = threadIdx.x;
    int lane = t & 63;
    int w = t >> 6;
    size_t row0 = (size_t)blockIdx.x * BMg;

    const unsigned short* Ag = (const unsigned short*)A;
    const unsigned short* Sg = (const unsigned short*)Aself;
    const unsigned short* Bg = (const unsigned short*)Bt;

    float bb[4];
#pragma unroll
    for (int ni = 0; ni < 4; ni++) bb[ni] = bias[w * 64 + ni * 16 + (lane & 15)];

    f32x4 acc[4][4] = {};

    auto issue_tile = [&](int k0, short* as, short* bs) {
        const unsigned short* Abase;
        int kk, stride;
        if (k0 < KMEAN) { Abase = Ag; kk = k0; stride = KMEAN; }
        else            { Abase = Sg; kk = k0 - KMEAN; stride = DIM; }
#pragma unroll
        for (int h = 0; h < 2; h++) {              // A: 512 chunks of 16B
            int c = t + h * 256;
            int r = c >> 3, pl = c & 7, pg = pl ^ (r & 7);
            const unsigned short* ga = Abase + (row0 + r) * stride + kk + pg * 8;
            __builtin_amdgcn_global_load_lds(
                (const __attribute__((address_space(1))) void*)ga,
                (__attribute__((address_space(3))) void*)((char*)as + c * 16),
                16, 0, 0);
        }
#pragma unroll
        for (int h = 0; h < 8; h++) {              // B: 2048 chunks of 16B
            int c = t + h * 256;
            int r = c >> 3, pl = c & 7, pg = pl ^ (r & 7);
            const unsigned short* gb = Bg + (size_t)r * KDIM + k0 + pg * 8;
            __builtin_amdgcn_global_load_lds(
                (const __attribute__((address_space(1))) void*)gb,
                (__attribute__((address_space(3))) void*)((char*)bs + c * 16),
                16, 0, 0);
        }
    };

    issue_tile(0, As[0], Bs[0]);
    int cur = 0;
    for (int k0 = 0; k0 < KDIM; k0 += BKg) {
        __syncthreads();                           // drains this tile's loads
        if (k0 + BKg < KDIM) issue_tile(k0 + BKg, As[cur ^ 1], Bs[cur ^ 1]);
        const short* as = As[cur];
        const short* bs = Bs[cur];
#pragma unroll
        for (int ks = 0; ks < 2; ks++) {
            int p = ks * 4 + (lane >> 4);          // 16B part index 0..7
            bf16x8 af[4], bfr[4];
#pragma unroll
            for (int mi = 0; mi < 4; mi++) {
                int m = mi * 16 + (lane & 15);
                af[mi] = *(const bf16x8*)&as[m * 64 + (p ^ (m & 7)) * 8];
            }
#pragma unroll
            for (int ni = 0; ni < 4; ni++) {
                int n = w * 64 + ni * 16 + (lane & 15);
                bfr[ni] = *(const bf16x8*)&bs[n * 64 + (p ^ (n & 7)) * 8];
            }
#pragma unroll
            for (int mi = 0; mi < 4; mi++)
#pragma unroll
                for (int ni = 0; ni < 4; ni++)
                    acc[mi][ni] = __builtin_amdgcn_mfma_f32_16x16x32_bf16(af[mi], bfr[ni], acc[mi][ni], 0, 0, 0);
        }
        cur ^= 1;
    }

    // C/D layout: col=lane&15, row=(lane>>4)*4+j  [m89-verified]
    if (MODE == 0) {
#pragma unroll
        for (int mi = 0; mi < 4; mi++) {
#pragma unroll
            for (int j = 0; j < 4; j++) {
                size_t row = row0 + mi * 16 + (lane >> 4) * 4 + j;
                if (row < (size_t)Nrows) {
#pragma unroll
                    for (int ni = 0; ni < 4; ni++) {
                        size_t col = w * 64 + ni * 16 + (lane & 15);
                        float v = fmaxf(acc[mi][ni][j] + bb[ni], 0.f);
                        __builtin_nontemporal_store(f2bf(v), Cbf + row * DIM + col);
                    }
                }
            }
        }
    } else {
        float cs[4] = {};
#pragma unroll
        for (int ni = 0; ni < 4; ni++) {
#pragma unroll
            for (int mi = 0; mi < 4; mi++)
#pragma unroll
                for (int j = 0; j < 4; j++) {
                    size_t row = row0 + mi * 16 + (lane >> 4) * 4 + j;
                    if (row < (size_t)Nrows) cs[ni] += acc[mi][ni][j] + bb[ni];
                }
            cs[ni] += __shfl_xor(cs[ni], 16, 64);
            cs[ni] += __shfl_xor(cs[ni], 32, 64);
        }
        if (lane < 16) {
#pragma unroll
            for (int ni = 0; ni < 4; ni++)
                atomicAdd(&gsum[w * 64 + ni * 16 + lane], cs[ni]);
        }
    }
}

// ---------------- linear head ----------------

__global__ void final_lin(const float* __restrict__ g, const float* __restrict__ lw,
                          const float* __restrict__ lb, float* __restrict__ out) {
    __shared__ float s0[256], s1[256];
    int t = threadIdx.x;
    float gv = g[t];
    s0[t] = gv * lw[t * 2 + 0];
    s1[t] = gv * lw[t * 2 + 1];
    __syncthreads();
    for (int off = 128; off > 0; off >>= 1) {
        if (t < off) { s0[t] += s0[t + off]; s1[t] += s1[t + off]; }
        __syncthreads();
    }
    if (t == 0) { out[0] = s0[0] + lb[0]; out[1] = s1[0] + lb[1]; }
}

// ---------------- launch ----------------

static inline char* align_up(char* p, size_t a) {
    return (char*)(((uintptr_t)p + (a - 1)) & ~(uintptr_t)(a - 1));
}

extern "C" void kernel_launch(void* const* d_in, const int* in_sizes, int n_in,
                              void* d_out, int out_size, void* d_ws, size_t ws_size,
                              hipStream_t stream) {
    const float* x     = (const float*)d_in[0];
    const int*   eidx  = (const int*)d_in[1];
    const int*   etype = (const int*)d_in[2];
    const float* W0    = (const float*)d_in[4];
    const float* root0 = (const float*)d_in[5];
    const float* b0    = (const float*)d_in[6];
    const float* W1    = (const float*)d_in[7];
    const float* root1 = (const float*)d_in[8];
    const float* b1    = (const float*)d_in[9];
    const float* lin_w = (const float*)d_in[10];
    const float* lin_b = (const float*)d_in[11];
    float* out = (float*)d_out;

    const int N = in_sizes[0] / DIM;
    const int E = in_sizes[2];
    const int RN = RREL * N;
    const int* src = eidx;
    const int* dst = eidx + E;

    const int gx = (N + BMg - 1) / BMg;
    const int Mpad = gx * BMg;

    char* w = (char*)d_ws;
    int* counts  = (int*)w; w += (size_t)RN * 4;
    float* g     = (float*)w; w += 256 * 4;
    size_t zero_bytes = (size_t)RN * 4 + 1024;   // counts + g, contiguous
    int* bucket  = (int*)w; w += (size_t)RN * BCAP * 4;
    w = align_up(w, 16);
    __hip_bfloat16* WT = (__hip_bfloat16*)w; w += (size_t)2 * DIM * KDIM * 2;
    w = align_up(w, 16);
    __hip_bfloat16* Y  = (__hip_bfloat16*)w; w += (size_t)Mpad * KMEAN * 2;
    __hip_bfloat16* xb = (__hip_bfloat16*)w; w += (size_t)Mpad * DIM * 2;
    __hip_bfloat16* h1 = (__hip_bfloat16*)w; w += (size_t)Mpad * DIM * 2;

    hipMemsetAsync(counts, 0, zero_bytes, stream);

    int eb = (E + 255) / 256;                 // scatter blocks
    int n4 = N * DIM / 4;
    int cb = (n4 + 255) / 256;                // cast blocks
    int wb = (KDIM / 32) * (DIM / 32) * 2;    // weight-transpose blocks (40*8*2)

    prep<<<eb + cb + wb, 256, 0, stream>>>(etype, src, dst, counts, bucket, N, E,
                                           x, xb, n4,
                                           W0, root0, W1, root1, WT, eb, cb);

    int ab = (N + 1) / 2;
    // layer 0: h1 = relu([Y|x] @ Wcat0 + b0), bf16
    aggregate<<<ab, 256, 0, stream>>>(xb, counts, bucket, Y, N);
    gemm_mfma<0><<<gx, 256, 0, stream>>>(Y, xb, WT, b0, (unsigned short*)h1, nullptr, N);
    // layer 1: g += colsum([Y|h1] @ Wcat1 + b1)  (h2 never materialized)
    aggregate<<<ab, 256, 0, stream>>>(h1, counts, bucket, Y, N);
    gemm_mfma<1><<<gx, 256, 0, stream>>>(Y, h1, WT + (size_t)DIM * KDIM, b1, nullptr, g, N);

    final_lin<<<1, 256, 0, stream>>>(g, lin_w, lin_b, out);
}

// Round 10
// 270.635 us; speedup vs baseline: 1.0594x; 1.0594x over previous
//
#include <hip/hip_runtime.h>
#include <hip/hip_bf16.h>

#define RREL 4
#define DIM 256
#define KDIM 1280      // 4*DIM (means) + DIM (self)
#define KMEAN 1024     // means-only K extent of Y
#define BCAP 32        // bucket capacity per (r,dst) segment

__device__ __forceinline__ float bf2f(unsigned short u) {
    union { unsigned int i; float f; } z; z.i = ((unsigned int)u) << 16; return z.f;
}
__device__ __forceinline__ unsigned short f2bf(float f) {
    __hip_bfloat16 h = __float2bfloat16(f);
    return *(unsigned short*)&h;
}

typedef __attribute__((ext_vector_type(8))) short bf16x8;
typedef __attribute__((ext_vector_type(8))) unsigned short u16x8;
typedef __attribute__((ext_vector_type(4))) float f32x4;
typedef __attribute__((ext_vector_type(4))) float fx4;

// ---------------- fused prep: bucket-scatter + x->bf16 cast + W0 transpose ----------
// No CSR scan: per-(r,dst) fixed-capacity bucket; counts doubles as cursor & final count.
// Only layer-0 weights need the n-major transpose (layer-1 GEMM is collapsed to a GEMV
// that reads W1/root1 in their native layout).

__global__ __launch_bounds__(256)
void prep(const int* __restrict__ etype, const int* __restrict__ src,
          const int* __restrict__ dst,
          int* __restrict__ counts, int* __restrict__ bucket, int N, int E,
          const float* __restrict__ x, __hip_bfloat16* __restrict__ xb, int n4,
          const float* __restrict__ W0, const float* __restrict__ root0,
          __hip_bfloat16* __restrict__ WT,
          int eb, int cb) {
    int b = blockIdx.x;
    if (b < eb) {                       // count + scatter into buckets
        int e = b * 256 + threadIdx.x;
        if (e < E) {
            int seg = etype[e] * N + dst[e];
            int p = atomicAdd(&counts[seg], 1);
            if (p < BCAP) bucket[(size_t)seg * BCAP + p] = src[e];
        }
    } else if (b < eb + cb) {           // cast x -> bf16
        int i = (b - eb) * 256 + threadIdx.x;
        if (i < n4) {
            fx4 v = *((const fx4*)x + i);
            ushort4 u = make_ushort4(f2bf(v.x), f2bf(v.y), f2bf(v.z), f2bf(v.w));
            ((ushort4*)xb)[i] = u;
        }
    } else {                            // WT[n=0..255][k=0..1279] n-major (layer 0)
        __shared__ float tile[32][33];
        int q = b - eb - cb;            // 0..319
        int nblk = q / 40;              // 0..7   (n0 over 256)
        int kblk = q - nblk * 40;       // 0..39  (k0 over 1280)
        int k0 = kblk * 32, n0 = nblk * 32;
        int tx = threadIdx.x & 31, ty = threadIdx.x >> 5;   // 32x8
        const float* srcp;
        int kbase;
        if (k0 < RREL * DIM) { srcp = W0; kbase = k0; } else { srcp = root0; kbase = k0 - RREL * DIM; }
#pragma unroll
        for (int j = 0; j < 4; j++) {
            int k = kbase + ty + j * 8;
            tile[ty + j * 8][tx] = srcp[(size_t)k * DIM + n0 + tx];
        }
        __syncthreads();
#pragma unroll
        for (int j = 0; j < 4; j++) {
            int n = n0 + ty + j * 8;
            WT[(size_t)n * KDIM + k0 + tx] = __float2bfloat16(tile[tx][ty + j * 8]);
        }
    }
}

// ---------------- aggregation (layer 0): Y[i,r*256:+256] = mean_r(xb)  (bf16) ----------------
// Block = node pair, wave = relation, half-wave = node (32 lanes x 8 dims = 256).
// Masked quad: one int4 bucket load + 4 independent 16B row loads in flight.
// Blocks >= ab: per-edge weight scatter for the collapsed layer 1:
//   w(s,r) += 1/cnt(r,dst)   (needs final counts -> must run after prep).

__global__ __launch_bounds__(256)
void aggregate(const __hip_bfloat16* __restrict__ feat, const int* __restrict__ counts,
               const int* __restrict__ bucket, __hip_bfloat16* __restrict__ Y, int N,
               const int* __restrict__ etype, const int* __restrict__ srcv,
               const int* __restrict__ dstv, float* __restrict__ wsr, int E, int ab) {
    if ((int)blockIdx.x >= ab) {        // edge-weight pass
        int e = (blockIdx.x - ab) * 256 + threadIdx.x;
        if (e < E) {
            int r = etype[e];
            int seg = r * N + dstv[e];
            float sc = 1.f / (float)counts[seg];
            atomicAdd(&wsr[(size_t)srcv[e] * RREL + r], sc);
        }
        return;
    }
    int r = threadIdx.x >> 6, lane = threadIdx.x & 63;
    int h = lane >> 5, li = lane & 31;
    int i = blockIdx.x * 2 + h;
    if (i >= N) return;
    int seg = r * N + i;
    int cnt = min(counts[seg], BCAP);
    const unsigned short* fu = (const unsigned short*)feat;
    const int* bk = bucket + (size_t)seg * BCAP;
    float a[8] = {};
    for (int k = 0; k < cnt; k += 4) {
        int4 q = *(const int4*)(bk + k);           // 16B-aligned
        float m1 = (k + 1 < cnt) ? 1.f : 0.f;
        float m2 = (k + 2 < cnt) ? 1.f : 0.f;
        float m3 = (k + 3 < cnt) ? 1.f : 0.f;
        int i0 = q.x;
        int i1 = m1 ? q.y : q.x;                   // clamp to a valid row address
        int i2 = m2 ? q.z : q.x;
        int i3 = m3 ? q.w : q.x;
        u16x8 v0 = *(const u16x8*)(fu + (size_t)i0 * DIM + li * 8);
        u16x8 v1 = *(const u16x8*)(fu + (size_t)i1 * DIM + li * 8);
        u16x8 v2 = *(const u16x8*)(fu + (size_t)i2 * DIM + li * 8);
        u16x8 v3 = *(const u16x8*)(fu + (size_t)i3 * DIM + li * 8);
#pragma unroll
        for (int j = 0; j < 8; j++)
            a[j] += bf2f(v0[j]) + m1 * bf2f(v1[j]) + m2 * bf2f(v2[j]) + m3 * bf2f(v3[j]);
    }
    float inv = (cnt > 0) ? 1.f / (float)cnt : 0.f;
    u16x8 u;
#pragma unroll
    for (int j = 0; j < 8; j++) u[j] = f2bf(a[j] * inv);
    *(u16x8*)((unsigned short*)Y + (size_t)i * KMEAN + r * DIM + li * 8) = u;
}

// ---------------- MFMA GEMM (layer 0 only), double-buffered, full-width N ----------------
// h1[N,256] = relu([Y | xb] @ WT^T + b0), bf16.  BM=64, BN=256 (Y fetched once), BK=64.

#define BMg 64
#define BKg 64

__global__ __launch_bounds__(256)
void gemm_mfma(const __hip_bfloat16* __restrict__ A,     // [Mpad, 1024] means
               const __hip_bfloat16* __restrict__ Aself, // [Mpad, 256] feature table
               const __hip_bfloat16* __restrict__ Bt,    // [256, 1280] n-major
               const float* __restrict__ bias,           // [256]
               unsigned short* __restrict__ Cbf,         // [N, 256]
               int Nrows) {
    __shared__ short As[2][BMg * BKg];       // 2 x 8 KB
    __shared__ short Bs[2][DIM * BKg];       // 2 x 32 KB
    int t = threadIdx.x;
    int lane = t & 63;
    int w = t >> 6;
    size_t row0 = (size_t)blockIdx.x * BMg;

    const unsigned short* Ag = (const unsigned short*)A;
    const unsigned short* Sg = (const unsigned short*)Aself;
    const unsigned short* Bg = (const unsigned short*)Bt;

    float bb[4];
#pragma unroll
    for (int ni = 0; ni < 4; ni++) bb[ni] = bias[w * 64 + ni * 16 + (lane & 15)];

    f32x4 acc[4][4] = {};

    auto issue_tile = [&](int k0, short* as, short* bs) {
        const unsigned short* Abase;
        int kk, stride;
        if (k0 < KMEAN) { Abase = Ag; kk = k0; stride = KMEAN; }
        else            { Abase = Sg; kk = k0 - KMEAN; stride = DIM; }
#pragma unroll
        for (int h = 0; h < 2; h++) {              // A: 512 chunks of 16B
            int c = t + h * 256;
            int r = c >> 3, pl = c & 7, pg = pl ^ (r & 7);
            const unsigned short* ga = Abase + (row0 + r) * stride + kk + pg * 8;
            __builtin_amdgcn_global_load_lds(
                (const __attribute__((address_space(1))) void*)ga,
                (__attribute__((address_space(3))) void*)((char*)as + c * 16),
                16, 0, 0);
        }
#pragma unroll
        for (int h = 0; h < 8; h++) {              // B: 2048 chunks of 16B
            int c = t + h * 256;
            int r = c >> 3, pl = c & 7, pg = pl ^ (r & 7);
            const unsigned short* gb = Bg + (size_t)r * KDIM + k0 + pg * 8;
            __builtin_amdgcn_global_load_lds(
                (const __attribute__((address_space(1))) void*)gb,
                (__attribute__((address_space(3))) void*)((char*)bs + c * 16),
                16, 0, 0);
        }
    };

    issue_tile(0, As[0], Bs[0]);
    int cur = 0;
    for (int k0 = 0; k0 < KDIM; k0 += BKg) {
        __syncthreads();                           // drains this tile's loads
        if (k0 + BKg < KDIM) issue_tile(k0 + BKg, As[cur ^ 1], Bs[cur ^ 1]);
        const short* as = As[cur];
        const short* bs = Bs[cur];
#pragma unroll
        for (int ks = 0; ks < 2; ks++) {
            int p = ks * 4 + (lane >> 4);          // 16B part index 0..7
            bf16x8 af[4], bfr[4];
#pragma unroll
            for (int mi = 0; mi < 4; mi++) {
                int m = mi * 16 + (lane & 15);
                af[mi] = *(const bf16x8*)&as[m * 64 + (p ^ (m & 7)) * 8];
            }
#pragma unroll
            for (int ni = 0; ni < 4; ni++) {
                int n = w * 64 + ni * 16 + (lane & 15);
                bfr[ni] = *(const bf16x8*)&bs[n * 64 + (p ^ (n & 7)) * 8];
            }
#pragma unroll
            for (int mi = 0; mi < 4; mi++)
#pragma unroll
                for (int ni = 0; ni < 4; ni++)
                    acc[mi][ni] = __builtin_amdgcn_mfma_f32_16x16x32_bf16(af[mi], bfr[ni], acc[mi][ni], 0, 0, 0);
        }
        cur ^= 1;
    }

    // C/D layout: col=lane&15, row=(lane>>4)*4+j  [m89-verified]
#pragma unroll
    for (int mi = 0; mi < 4; mi++) {
#pragma unroll
        for (int j = 0; j < 4; j++) {
            size_t row = row0 + mi * 16 + (lane >> 4) * 4 + j;
            if (row < (size_t)Nrows) {
#pragma unroll
                for (int ni = 0; ni < 4; ni++) {
                    size_t col = w * 64 + ni * 16 + (lane & 15);
                    float v = fmaxf(acc[mi][ni][j] + bb[ni], 0.f);
                    Cbf[row * DIM + col] = f2bf(v);
                }
            }
        }
    }
}

// ---------------- collapsed layer 1, stage A: weighted column sums over h1 ----------------
// sv[r*256+c] = sum_i w(i,r) * h1[i][c]   (r=0..3, the relation mean sums)
// sv[1024+c]  = sum_i h1[i][c]            (the root/self sum)

__global__ __launch_bounds__(256)
void wcolsum(const unsigned short* __restrict__ h1, const float* __restrict__ wsr,
             int N, float* __restrict__ sv) {
    int t = threadIdx.x;
    int i0 = blockIdx.x * 256;
    int iend = min(i0 + 256, N);
    float a0 = 0.f, a1 = 0.f, a2 = 0.f, a3 = 0.f, as = 0.f;
#pragma unroll 4
    for (int i = i0; i < iend; i++) {
        float v = bf2f(h1[(size_t)i * DIM + t]);
        fx4 wv = *(const fx4*)(wsr + (size_t)i * RREL);
        as += v;
        a0 += wv.x * v; a1 += wv.y * v; a2 += wv.z * v; a3 += wv.w * v;
    }
    atomicAdd(&sv[0 * DIM + t], a0);
    atomicAdd(&sv[1 * DIM + t], a1);
    atomicAdd(&sv[2 * DIM + t], a2);
    atomicAdd(&sv[3 * DIM + t], a3);
    atomicAdd(&sv[4 * DIM + t], as);
}

// ---------------- collapsed layer 1, stage B: GEMV  g = sv @ Wcat1 + N*b1 ----------------
// k-split across blocks; W1/root1 read in native [k][n] layout (no transpose needed).

__global__ __launch_bounds__(256)
void gemv(const float* __restrict__ sv, const float* __restrict__ W1,
          const float* __restrict__ root1, const float* __restrict__ b1,
          int N, float* __restrict__ g) {
    int t = threadIdx.x;
    int kk0 = blockIdx.x * 64;
    float acc = 0.f;
    for (int kk = kk0; kk < kk0 + 64; kk++) {
        int r = kk >> 8;                 // 0..4
        int k = kk & 255;
        const float* row = (r < RREL) ? (W1 + ((size_t)r * DIM + k) * DIM)
                                      : (root1 + (size_t)k * DIM);
        acc += sv[kk] * row[t];
    }
    if (blockIdx.x == 0) acc += (float)N * b1[t];
    atomicAdd(&g[t], acc);
}

// ---------------- linear head ----------------

__global__ void final_lin(const float* __restrict__ g, const float* __restrict__ lw,
                          const float* __restrict__ lb, float* __restrict__ out) {
    __shared__ float s0[256], s1[256];
    int t = threadIdx.x;
    float gv = g[t];
    s0[t] = gv * lw[t * 2 + 0];
    s1[t] = gv * lw[t * 2 + 1];
    __syncthreads();
    for (int off = 128; off > 0; off >>= 1) {
        if (t < off) { s0[t] += s0[t + off]; s1[t] += s1[t + off]; }
        __syncthreads();
    }
    if (t == 0) { out[0] = s0[0] + lb[0]; out[1] = s1[0] + lb[1]; }
}

// ---------------- launch ----------------

static inline char* align_up(char* p, size_t a) {
    return (char*)(((uintptr_t)p + (a - 1)) & ~(uintptr_t)(a - 1));
}

extern "C" void kernel_launch(void* const* d_in, const int* in_sizes, int n_in,
                              void* d_out, int out_size, void* d_ws, size_t ws_size,
                              hipStream_t stream) {
    const float* x     = (const float*)d_in[0];
    const int*   eidx  = (const int*)d_in[1];
    const int*   etype = (const int*)d_in[2];
    const float* W0    = (const float*)d_in[4];
    const float* root0 = (const float*)d_in[5];
    const float* b0    = (const float*)d_in[6];
    const float* W1    = (const float*)d_in[7];
    const float* root1 = (const float*)d_in[8];
    const float* b1    = (const float*)d_in[9];
    const float* lin_w = (const float*)d_in[10];
    const float* lin_b = (const float*)d_in[11];
    float* out = (float*)d_out;

    const int N = in_sizes[0] / DIM;
    const int E = in_sizes[2];
    const int RN = RREL * N;
    const int* src = eidx;
    const int* dst = eidx + E;

    const int gx = (N + BMg - 1) / BMg;
    const int Mpad = gx * BMg;

    char* w = (char*)d_ws;
    int*   counts = (int*)w;   w += (size_t)RN * 4;
    float* wsr    = (float*)w; w += (size_t)N * RREL * 4;
    float* sv     = (float*)w; w += (size_t)5 * DIM * 4;
    float* g      = (float*)w; w += 256 * 4;
    size_t zero_bytes = (size_t)RN * 4 + (size_t)N * RREL * 4 + 5 * DIM * 4 + 256 * 4;
    int* bucket = (int*)w; w += (size_t)RN * BCAP * 4;
    w = align_up(w, 16);
    __hip_bfloat16* WT = (__hip_bfloat16*)w; w += (size_t)DIM * KDIM * 2;
    w = align_up(w, 16);
    __hip_bfloat16* Y  = (__hip_bfloat16*)w; w += (size_t)Mpad * KMEAN * 2;
    __hip_bfloat16* xb = (__hip_bfloat16*)w; w += (size_t)Mpad * DIM * 2;
    __hip_bfloat16* h1 = (__hip_bfloat16*)w; w += (size_t)Mpad * DIM * 2;

    hipMemsetAsync(counts, 0, zero_bytes, stream);

    int eb = (E + 255) / 256;                 // scatter / edge-weight blocks
    int n4 = N * DIM / 4;
    int cb = (n4 + 255) / 256;                // cast blocks
    int wb = (KDIM / 32) * (DIM / 32);        // W0-transpose blocks (40*8)

    prep<<<eb + cb + wb, 256, 0, stream>>>(etype, src, dst, counts, bucket, N, E,
                                           x, xb, n4, W0, root0, WT, eb, cb);

    int ab = (N + 1) / 2;
    // layer 0 aggregate (+ fused edge-weight pass for collapsed layer 1)
    aggregate<<<ab + eb, 256, 0, stream>>>(xb, counts, bucket, Y, N,
                                           etype, src, dst, wsr, E, ab);
    // layer 0 GEMM: h1 = relu([Y|xb] @ Wcat0 + b0)
    gemm_mfma<<<gx, 256, 0, stream>>>(Y, xb, WT, b0, (unsigned short*)h1, N);
    // collapsed layer 1: g = sv @ Wcat1 + N*b1,  sv = weighted colsums of h1
    wcolsum<<<(N + 255) / 256, 256, 0, stream>>>((const unsigned short*)h1, wsr, N, sv);
    gemv<<<KDIM / 64, 256, 0, stream>>>(sv, W1, root1, b1, N, g);

    final_lin<<<1, 256, 0, stream>>>(g, lin_w, lin_b, out);
}